// Round 3
// baseline (258.085 us; speedup 1.0000x reference)
//
#include <hip/hip_runtime.h>
#include <hip/hip_bf16.h>

// TensorTrainLMN: out[b, a*128+h] = X[b,:] @ W[:, a*128+h] + bias
//   X[b] = [nh[b,0,:128], ..., nh[b,15,:128], te[b,:128]]   (K = 2176)
// tt_fold: folds A@B^(15-c)@U_out (exact f32) into W, stored bf16 PRE-PACKED
//   in the GEMM's LDS tile image: [n_blk][kt][slot=k/8][n_loc][8 bf16].
// tt_gemm: 256x256x64 bf16 MFMA GEMM, 2-phase counted schedule (T3/T4 min):
//   stores+sync have zero outstanding vm ops; loads for kt+1 issued after the
//   barrier and waited only after compute(kt) -> HBM streams under MFMA.
//   k-slot-major LDS [slot][row][8bf16] -> conflict-free ds_read_b128 frags.

typedef short bf16x8 __attribute__((ext_vector_type(8)));
typedef float f32x4  __attribute__((ext_vector_type(4)));

__device__ __forceinline__ unsigned f2bfbits(float f) {
    unsigned u = __builtin_bit_cast(unsigned, f);
    return (u + 0x7FFFu + ((u >> 16) & 1u)) >> 16;   // round-to-nearest-even
}
__device__ __forceinline__ unsigned pack2(float a, float b) {
    return f2bfbits(a) | (f2bfbits(b) << 16);
}

// ---------------------------------------------------------------------------
// Fold kernel: 72 blocks x 256 threads (same math as round-2 verified kernel;
// only the W output indexing changed to the pre-packed tile image).
// ---------------------------------------------------------------------------
__global__ __launch_bounds__(256) void tt_fold(
    const float* __restrict__ Ag,    // (4,128,64)
    const float* __restrict__ Bg,    // (4,64,64)
    const float* __restrict__ Abg,   // (4,1,64)
    const float* __restrict__ Utg,   // (4,128,64)
    const float* __restrict__ btg,   // (4,1,64)
    const float* __restrict__ Uog,   // (4,64,128)
    const float* __restrict__ bog,   // (4,1,128)
    unsigned short* __restrict__ Wp, // pre-packed W tile image (2*34*16384 shorts)
    float* __restrict__ biasOut)     // [512]
{
    __shared__ __align__(16) float L[16384];
    const int t = threadIdx.x;
    const int bid = blockIdx.x;

    auto mm = [&](float* d, const float* x, const float* y, const float* add) {
        const int r = t >> 2, c0 = (t & 3) << 4;
        float acc[16];
#pragma unroll
        for (int j = 0; j < 16; ++j) acc[j] = 0.f;
        for (int k = 0; k < 64; ++k) {
            const float a = x[r * 64 + k];
            const float4* yr = (const float4*)(y + k * 64 + c0);
#pragma unroll
            for (int jj = 0; jj < 4; ++jj) {
                float4 v = yr[jj];
                acc[4 * jj + 0] += a * v.x;
                acc[4 * jj + 1] += a * v.y;
                acc[4 * jj + 2] += a * v.z;
                acc[4 * jj + 3] += a * v.w;
            }
        }
        if (add) {
#pragma unroll
            for (int j = 0; j < 16; ++j) acc[j] += add[r * 64 + c0 + j];
        }
#pragma unroll
        for (int j = 0; j < 16; ++j) d[r * 64 + c0 + j] = acc[j];
    };

    float* buf[4];
    buf[0] = L;
    buf[1] = L + 4096;
    buf[2] = L + 8192;
    buf[3] = L + 12288;

    if (bid < 68) {
        int a, p, kbase;
        const float* src;
        if (bid < 64) { a = bid >> 4; const int c = bid & 15; p = 15 - c; kbase = c * 128; src = Ag  + a * 8192; }
        else          { a = bid - 64; p = 16; kbase = 2048;               src = Utg + a * 8192; }
        const float* Bmat = Bg + a * 4096;

        for (int i = t; i < 4096; i += 256) {
            buf[0][i] = Bmat[i];
            buf[2][i] = ((i >> 6) == (i & 63)) ? 1.f : 0.f;
        }
        __syncthreads();
        int bcur = 0, rcur = 2;
        int e = p;
        while (e) {
            if (e & 1) { mm(buf[rcur ^ 1], buf[rcur], buf[bcur], nullptr); rcur ^= 1; __syncthreads(); }
            e >>= 1;
            if (e)     { mm(buf[bcur ^ 1], buf[bcur], buf[bcur], nullptr); bcur ^= 1; __syncthreads(); }
        }

        {
            float tmp[16];
#pragma unroll
            for (int j = 0; j < 16; ++j) tmp[j] = buf[rcur][t * 16 + j];
            __syncthreads();
            float* P = L + 8320;
#pragma unroll
            for (int j = 0; j < 16; ++j) P[t * 16 + j] = tmp[j];
        }
        __syncthreads();

        // M1 = src(128x64) @ P, stride-65
        const float* P = L + 8320;
        float* M1 = L;
        {
            const int i = t >> 1, r0 = (t & 1) << 5;
            float acc[32];
#pragma unroll
            for (int j = 0; j < 32; ++j) acc[j] = 0.f;
            for (int q = 0; q < 64; ++q) {
                const float av = src[i * 64 + q];
                const float4* pr = (const float4*)(P + q * 64 + r0);
#pragma unroll
                for (int jj = 0; jj < 8; ++jj) {
                    float4 v = pr[jj];
                    acc[4 * jj + 0] += av * v.x;
                    acc[4 * jj + 1] += av * v.y;
                    acc[4 * jj + 2] += av * v.z;
                    acc[4 * jj + 3] += av * v.w;
                }
            }
#pragma unroll
            for (int j = 0; j < 32; ++j) M1[i * 65 + r0 + j] = acc[j];
        }
        __syncthreads();

        // W2 = M1(128x64) @ Uo(64x128)
        const float* UoA = Uog + a * 8192;
        float* UC = L + 12416;
        const int i = t >> 1, h0 = (t & 1) << 6;
        float acc2[64];
#pragma unroll
        for (int j = 0; j < 64; ++j) acc2[j] = 0.f;
        for (int ch = 0; ch < 4; ++ch) {
            __syncthreads();
            for (int idx = t; idx < 2048; idx += 256) UC[idx] = UoA[ch * 2048 + idx];
            __syncthreads();
            for (int rr = 0; rr < 16; ++rr) {
                const float m = M1[i * 65 + ch * 16 + rr];
                const float4* ur = (const float4*)(UC + rr * 128 + h0);
#pragma unroll
                for (int jj = 0; jj < 16; ++jj) {
                    float4 v = ur[jj];
                    acc2[4 * jj + 0] += m * v.x;
                    acc2[4 * jj + 1] += m * v.y;
                    acc2[4 * jj + 2] += m * v.z;
                    acc2[4 * jj + 3] += m * v.w;
                }
            }
        }
        // write into pre-packed tile image: k = kbase+i fixed per thread
        {
            const int k = kbase + i;
            const int kt = k >> 6, slot = (k >> 3) & 7, widx = k & 7;
#pragma unroll
            for (int j = 0; j < 64; ++j) {
                const int n = a * 128 + h0 + j;
                const int n_blk = n >> 8, n_loc = n & 255;
                Wp[(size_t)((n_blk * 34 + kt) * 8 + slot) * 2048 + n_loc * 8 + widx] =
                    (unsigned short)f2bfbits(acc2[j]);
            }
        }
    } else {
        // bias: S16 = sum_{p<16} B^p, B16 = B^16
        const int a = bid - 68;
        const float* Bmat = Bg + a * 4096;
        for (int i = t; i < 4096; i += 256) {
            buf[0][i] = Bmat[i];
            buf[2][i] = ((i >> 6) == (i & 63)) ? 1.f : 0.f;
        }
        __syncthreads();
        int bcur = 0, scur = 2;
        for (int rnd = 0; rnd < 4; ++rnd) {
            mm(buf[scur ^ 1], buf[bcur], buf[scur], buf[scur]);
            mm(buf[bcur ^ 1], buf[bcur], buf[bcur], nullptr);
            __syncthreads();
            scur ^= 1; bcur ^= 1;
        }
        float* vv = buf[3];
        if (t < 64) {
            float acc = 0.f;
            const float* S16 = buf[scur];
            const float* B16 = buf[bcur];
            for (int q = 0; q < 64; ++q)
                acc += Abg[a * 64 + q] * S16[q * 64 + t]
                     + btg[a * 64 + q] * B16[q * 64 + t];
            vv[t] = acc;
        }
        __syncthreads();
        if (t < 128) {
            float accb = bog[a * 128 + t];
            const float* UoA = Uog + a * 8192;
            for (int r = 0; r < 64; ++r) accb += vv[r] * UoA[r * 128 + t];
            biasOut[a * 128 + t] = accb;
        }
    }
}

// ---------------------------------------------------------------------------
// Main GEMM: out[32768,512] = X(f32->bf16) @ W(bf16, pre-packed) + bias
// BM=BN=256, BK=64, 34 K-tiles, 512 threads (8 waves 2x4), wave tile 128x64,
// 1 block/CU, 128 KiB LDS double-buffered, 2-phase counted schedule.
// ---------------------------------------------------------------------------
__global__ __launch_bounds__(512, 2) void tt_gemm(
    const float* __restrict__ nh,           // (32768,16,128)
    const float* __restrict__ te,           // (32768,128)
    const unsigned short* __restrict__ Wp,  // pre-packed tiles
    const float* __restrict__ bias,         // [512]
    float* __restrict__ out)                // (32768,512)
{
    __shared__ __align__(16) char Lds[131072];   // A: 2x32K @0, B: 2x32K @64K

    const int t = threadIdx.x;
    const int hw = blockIdx.x;
    // chunked XCD map: XCD x owns 32 consecutive logical tiles ->
    // both N-halves of each X-panel co-resident on one XCD (L2 X reuse).
    const int lt = (hw & 7) * 32 + (hw >> 3);   // bijective, 256 = 8*32
    const int m0 = (lt >> 1) * 256;
    const int nblk = lt & 1;
    const int n0 = nblk * 256;

    const int wave = t >> 6, lane = t & 63;
    const int wr = wave >> 2, wc = wave & 3;     // 2(M) x 4(N) wave grid
    const int lx = lane & 15, lg = lane >> 4;

    // A staging: thread -> row r=t>>1 (0..255), k-half h=t&1 (32 floats)
    const int r = t >> 1, h = t & 1;
    const float* nhp = nh + (size_t)(m0 + r) * 2048 + h * 32;
    const float* tep = te + (size_t)(m0 + r) * 128  + h * 32;
    // B staging: thread reads 64 contiguous bytes of the pre-packed tile
    const unsigned short* wpt = Wp + (size_t)nblk * 34 * 16384 + t * 32;

    f32x4 acc[8][4] = {};

    float4 fa[8];
    uint4  fb[4];

    auto issueA = [&](int kt) {
        const float* p = (kt < 32) ? (nhp + kt * 64) : (tep + (kt - 32) * 64);
#pragma unroll
        for (int j = 0; j < 8; ++j) fa[j] = *(const float4*)(p + 4 * j);
    };
    auto issueB = [&](int kt) {
        const unsigned short* q = wpt + (size_t)kt * 16384;
#pragma unroll
        for (int j = 0; j < 4; ++j) fb[j] = *(const uint4*)(q + 8 * j);
    };

    char* const Abase = Lds;                 // [buf][slot 0..7][row 0..255][16B]
    char* const Bbase = Lds + 65536;         // [buf][slot 0..7][nloc 0..255][16B]
    char* const aw = Abase + h * 16384 + r * 16;   // + j*4096 + buf*32768
    char* const bw = Bbase + t * 64;               // + j*16   + buf*32768

    issueB(0);
    issueA(0);

    int buf = 0;
    for (int kt = 0; kt < 34; ++kt) {
        // --- store phase: compiler waits (counted) on the in-flight loads ---
        {
            char* w = bw + buf * 32768;
#pragma unroll
            for (int j = 0; j < 4; ++j) *(uint4*)(w + j * 16) = fb[j];
        }
        {
            char* w = aw + buf * 32768;
#pragma unroll
            for (int j = 0; j < 4; ++j) {
                uint4 v;
                v.x = pack2(fa[2 * j].x,     fa[2 * j].y);
                v.y = pack2(fa[2 * j].z,     fa[2 * j].w);
                v.z = pack2(fa[2 * j + 1].x, fa[2 * j + 1].y);
                v.w = pack2(fa[2 * j + 1].z, fa[2 * j + 1].w);
                *(uint4*)(w + j * 4096) = v;
            }
        }
        __syncthreads();   // no outstanding vm ops here -> drain is free

        // --- issue next tile's loads: stream HBM under the MFMA phase ---
        if (kt + 1 < 34) { issueB(kt + 1); issueA(kt + 1); }

        // --- compute phase: 24 conflict-free ds_read_b128 + 64 MFMA ---
        const char* Ar = Abase + buf * 32768 + lg * 4096 + (wr * 128 + lx) * 16;
        const char* Br = Bbase + buf * 32768 + lg * 4096 + (wc * 64  + lx) * 16;
#pragma unroll
        for (int kk = 0; kk < 2; ++kk) {
            bf16x8 bF[4];
#pragma unroll
            for (int fn = 0; fn < 4; ++fn)
                bF[fn] = *(const bf16x8*)(Br + kk * 16384 + fn * 256);
#pragma unroll
            for (int fm = 0; fm < 8; ++fm) {
                bf16x8 aF = *(const bf16x8*)(Ar + kk * 16384 + fm * 256);
#pragma unroll
                for (int fn = 0; fn < 4; ++fn)
                    acc[fm][fn] = __builtin_amdgcn_mfma_f32_16x16x32_bf16(
                        aF, bF[fn], acc[fm][fn], 0, 0, 0);
            }
        }
        buf ^= 1;
    }

    // epilogue: C/D layout col = lane&15, row = (lane>>4)*4 + reg  [m89]
    const int orow = m0 + wr * 128 + lg * 4;
    const int ocol = n0 + wc * 64 + lx;
    float bv[4];
#pragma unroll
    for (int fn = 0; fn < 4; ++fn) bv[fn] = bias[ocol + fn * 16];
#pragma unroll
    for (int fm = 0; fm < 8; ++fm)
#pragma unroll
        for (int fn = 0; fn < 4; ++fn)
#pragma unroll
            for (int j = 0; j < 4; ++j)
                out[(size_t)(orow + fm * 16 + j) * 512 + ocol + fn * 16] =
                    acc[fm][fn][j] + bv[fn];
}

// ---------------------------------------------------------------------------
extern "C" void kernel_launch(void* const* d_in, const int* in_sizes, int n_in,
                              void* d_out, int out_size, void* d_ws, size_t ws_size,
                              hipStream_t stream) {
    const float* nh  = (const float*)d_in[0];
    const float* te  = (const float*)d_in[1];
    const float* Ag  = (const float*)d_in[2];
    const float* Bg  = (const float*)d_in[3];
    const float* Abg = (const float*)d_in[4];
    const float* Utg = (const float*)d_in[5];
    const float* btg = (const float*)d_in[6];
    const float* Uog = (const float*)d_in[7];
    const float* bog = (const float*)d_in[8];

    unsigned short* Wp = (unsigned short*)d_ws;              // 2*34*16384*2 B
    float* bias = (float*)((char*)d_ws + (size_t)2 * 34 * 16384 * 2);
    float* out = (float*)d_out;

    hipLaunchKernelGGL(tt_fold, dim3(72), dim3(256), 0, stream,
                       Ag, Bg, Abg, Utg, btg, Uog, bog, Wp, bias);
    hipLaunchKernelGGL(tt_gemm, dim3(256), dim3(512), 0, stream,
                       nh, te, Wp, bias, out);
}